// Round 7
// baseline (675.120 us; speedup 1.0000x reference)
//
#include <hip/hip_runtime.h>

// BatchConv2DLayer: per-sample 3x3 conv, stride 1, pad 1, fp32 in/out.
// SINGLE kernel, workspace-free (experiment: avoid harness ws re-poison
// fills, 2 x 1GiB x ~164us inside the timed window).
// conv_fused_kernel: 16x32 output tile, 512 thr. Reads x (NCHW fp32)
// directly, v_cvt_pk_bf16_f32 -> XOR-swizzled LDS NHWC tile
// (ds_write_b128), implicit-GEMM mfma_f32_16x16x32_bf16 with A=pixels /
// B=weights so D rows = 4 consecutive w -> dwordx4 stores. Weight frags
// converted in-register from fp32 global (L2-hot via XCD clustering).
// Flat grid + XCD-aware remap: each XCD owns 4 images; th innermost so
// halo-sharing neighbor tiles hit the same XCD-private L2.

#define BB 32
#define CI 32
#define CO 32
#define HH 256
#define WW 256

typedef unsigned int uint;
using short8  = __attribute__((ext_vector_type(8))) short;
using float4v = __attribute__((ext_vector_type(4))) float;

union U16 { uint4 u; short8 s; };

// v_cvt_pk_bf16_f32: lo -> D[15:0], hi -> D[31:16], RNE (no builtin on gfx950)
__device__ inline uint pk2bf(float lo, float hi) {
    uint r;
    asm("v_cvt_pk_bf16_f32 %0, %1, %2" : "=v"(r) : "v"(lo), "v"(hi));
    return r;
}

// ---------------------------------------------------------------------------
// Block = (b, 16-row x 32-col tile), 512 thr (8 waves). LDS x tile 18 rows
// x 40 aligned cols x 32ci bf16 = 46080 B (tile col c <-> w = w0 + c - 4).
// Swizzle: ci-quad q of pixel p stored at quad-slot q ^ ((p>>1)&3)
// (same involution on ds_write and ds_read).
// Staging item (rr, f, ciq): 8x float4 global loads (ci=ciq*8+j, 4 cols),
// cvt_pk to bf16, 4x swizzled ds_write_b128 (one per pixel).
// Weights: per lane, frag [co=lp or 16+lp][tap][ci=lq*8..+7] built from 16
// fp32 dword loads (stride 9 floats) + 8 cvt_pk per tap. 36KB/image, L2-hot.
// Compute: wave wv owns pixel-groups wv*4..+3, both co halves: per tap one
// swizzled ds_read_b128 pixel-frag feeds 2 MFMAs (A=pixels, B=weights).
// mfma_f32_16x16x32_bf16 layouts (guide §3, m89/m91-verified):
//   A[m=lane&15][k=(lane>>4)*8+j]  (m=pixel, k=ci)
//   B[k=(lane>>4)*8+j][n=lane&15]  (n=co)
//   D: col(n=co)=lane&15, row(m=pixel)=(lane>>4)*4+reg -> 4 consecutive w
// Grid: flat 4096. Remap (bijective): xcd=bid&7 owns images 4*xcd..4*xcd+3;
// within an XCD blocks run th-innermost then tw -> row-halo neighbors are
// adjacent in issue order, col-halo neighbors 16 apart (<< L2 window).
// ---------------------------------------------------------------------------
#define TH 16
#define TW 32
#define XR (TH + 2)   // 18 rows
#define XC 40         // aligned cols: w0-4 .. w0+35

__device__ inline int swz_us(int pix, int q) {
    // ushort index of 16B quad-slot q^((pix>>1)&3) of pixel pix
    return pix * CI + (((q ^ (pix >> 1)) & 3) << 3);
}

__global__ __launch_bounds__(512, 4)
void conv_fused_kernel(const float* __restrict__ x,
                       const float* __restrict__ wgt,
                       const float* __restrict__ bias,
                       float* __restrict__ out) {
    __shared__ __align__(16) unsigned short xs[XR * XC * CI];   // 46080 B

    // XCD-aware remap of the flat block id.
    const int bid   = blockIdx.x;          // 0..4095
    const int xcd   = bid & 7;             // assumes dispatch = bid % 8 (perf-only)
    const int idx   = bid >> 3;            // 0..511
    const int th    = idx & 15;            // row strip, innermost per XCD
    const int pairl = idx >> 4;            // 0..31
    const int pair  = xcd * 32 + pairl;    // 0..255 = b*8 + tw
    const int b     = pair >> 3;
    const int tw    = pair & 7;

    const int t  = threadIdx.x;
    const int h0 = th * TH, w0 = tw * TW;

    const int wv  = t >> 6;            // 0..7
    const int l   = t & 63;
    const int lp  = l & 15;            // A:m(pixel) == B:n(co)
    const int lq  = l >> 4;            // quad -> k = lq*8+j

    // ---- Fused staging: x fp32 NCHW -> swizzled bf16 NHWC tile in LDS ----
    // 720 items = 18 rows x 10 f4-cols x 4 ci-quads.
    const float* xb = x + (size_t)b * CI * HH * WW;
    for (int i = t; i < XR * 10 * 4; i += 512) {
        const int qd  = i / 10;          // 0..71
        const int f   = i - qd * 10;     // 0..9
        const int ciq = qd & 3;          // 0..3
        const int rr  = qd >> 2;         // 0..17
        const int h   = h0 - 1 + rr;
        const int c4  = w0 - 4 + 4 * f;
        float4v v[8];
        if (h >= 0 && h < HH && c4 >= 0 && c4 <= WW - 4) {
            const float* p0 = xb + (size_t)(ciq * 8) * HH * WW
                                 + (size_t)h * WW + c4;
            #pragma unroll
            for (int j = 0; j < 8; ++j)
                v[j] = *(const float4v*)(p0 + (size_t)j * HH * WW);
        } else {
            #pragma unroll
            for (int j = 0; j < 8; ++j) v[j] = {0.f, 0.f, 0.f, 0.f};
        }
        #pragma unroll
        for (int e = 0; e < 4; ++e) {
            const int p = rr * XC + 4 * f + e;
            uint4 pk;
            pk.x = pk2bf(v[0][e], v[1][e]);
            pk.y = pk2bf(v[2][e], v[3][e]);
            pk.z = pk2bf(v[4][e], v[5][e]);
            pk.w = pk2bf(v[6][e], v[7][e]);
            *(uint4*)(&xs[swz_us(p, ciq)]) = pk;
        }
    }

    // ---- Weight frags in-register from fp32 global (overlap barrier) ----
    // wgt layout [b][co][ci][kh][kw]; tap = kh*3+kw is innermost, stride
    // between ci values = 9 floats.
    const float* wgb = wgt + (size_t)(b * CO) * CI * 9;
    short8 W0[9], W1[9];
    #pragma unroll
    for (int tp = 0; tp < 9; ++tp) {
        const float* p0 = wgb + ((size_t)(lp)      * CI + lq * 8) * 9 + tp;
        const float* p1 = wgb + ((size_t)(16 + lp) * CI + lq * 8) * 9 + tp;
        U16 u0, u1;
        u0.u.x = pk2bf(p0[0 * 9], p0[1 * 9]);
        u0.u.y = pk2bf(p0[2 * 9], p0[3 * 9]);
        u0.u.z = pk2bf(p0[4 * 9], p0[5 * 9]);
        u0.u.w = pk2bf(p0[6 * 9], p0[7 * 9]);
        u1.u.x = pk2bf(p1[0 * 9], p1[1 * 9]);
        u1.u.y = pk2bf(p1[2 * 9], p1[3 * 9]);
        u1.u.z = pk2bf(p1[4 * 9], p1[5 * 9]);
        u1.u.w = pk2bf(p1[6 * 9], p1[7 * 9]);
        W0[tp] = u0.s;
        W1[tp] = u1.s;
    }
    const float bv0 = bias[b * CO + lp];
    const float bv1 = bias[b * CO + 16 + lp];

    __syncthreads();

    float4v acc0[4], acc1[4];
    #pragma unroll
    for (int g = 0; g < 4; ++g) {
        acc0[g] = {0.f, 0.f, 0.f, 0.f};
        acc1[g] = {0.f, 0.f, 0.f, 0.f};
    }

    #pragma unroll
    for (int g = 0; g < 4; ++g) {
        const int gg = wv * 4 + g;       // 0..31
        const int r  = gg >> 1;          // local output row 0..15
        const int c0 = (gg & 1) * 16;    // local output col base
        #pragma unroll
        for (int kh = 0; kh < 3; ++kh) {
            #pragma unroll
            for (int kw = 0; kw < 3; ++kw) {
                // input: global row h0+r+kh-1 = tile row r+kh;
                //        global col w0+c0+lp+kw-1 = tile col c0+lp+kw+3
                const int p = (r + kh) * XC + (c0 + lp + kw + 3);
                short8 Pf = *(const short8*)(&xs[swz_us(p, lq)]);
                acc0[g] = __builtin_amdgcn_mfma_f32_16x16x32_bf16(
                    Pf, W0[kh * 3 + kw], acc0[g], 0, 0, 0);
                acc1[g] = __builtin_amdgcn_mfma_f32_16x16x32_bf16(
                    Pf, W1[kh * 3 + kw], acc1[g], 0, 0, 0);
            }
        }
    }

    // Epilogue: lane holds co=lp (and 16+lp), pixels = c0 + lq*4 + v.
    #pragma unroll
    for (int g = 0; g < 4; ++g) {
        const int gg = wv * 4 + g;
        const int r  = gg >> 1;
        const int c0 = (gg & 1) * 16;
        const int h  = h0 + r;
        const int wb4 = w0 + c0 + lq * 4;
        float4v o0 = acc0[g] + bv0;
        float4v o1 = acc1[g] + bv1;
        *(float4v*)(&out[(((size_t)(b * CO + lp)) * HH + h) * WW + wb4]) = o0;
        *(float4v*)(&out[(((size_t)(b * CO + 16 + lp)) * HH + h) * WW + wb4]) = o1;
    }
}

extern "C" void kernel_launch(void* const* d_in, const int* in_sizes, int n_in,
                              void* d_out, int out_size, void* d_ws, size_t ws_size,
                              hipStream_t stream) {
    const float* x    = (const float*)d_in[0];
    const float* wgt  = (const float*)d_in[1];
    const float* bias = (const float*)d_in[2];
    float* out        = (float*)d_out;
    (void)d_ws; (void)ws_size;   // workspace intentionally unused

    hipLaunchKernelGGL(conv_fused_kernel,
                       dim3((WW / TW) * (HH / TH) * BB), dim3(512),
                       0, stream, x, wgt, bias, out);
}